// Round 8
// baseline (136.690 us; speedup 1.0000x reference)
//
#include <hip/hip_runtime.h>
#include <stdint.h>

typedef unsigned long long u64;
typedef unsigned int u32;

#define N_ANCH 36864
#define WGRID 64
#define A_PER 9
#define KTOP 6000
#define NOUT 300
#define NBIN 5120       // max used bin = 4352 (binof)
#define NCHK 94         // ceil(6000/64) = u64 words
#define NJ   6016       // padded j-stride of S (u64 words)
#define NSLOT 12        // named-register slots per wave (48 total; ~43 active expected)
#define SPILLCAP 64     // LDS overflow; 48+64 >= 94 chunks -> always correct
#define SCAP 6144       // LDS scat capacity (E ~ 6000; global fallback beyond)

// Raw barrier: LDS-drain only. Global prefetches stay in flight across it.
#define BARRIER_LDS() do {                                   \
    asm volatile("s_waitcnt lgkmcnt(0)" ::: "memory");       \
    __builtin_amdgcn_s_barrier();                            \
    asm volatile("" ::: "memory");                           \
} while (0)

// Base anchors from py-faster-rcnn generate_anchors (scales 8,16,32; ratios .5,1,2).
__constant__ float c_ax1[9] = {-84.f,-176.f,-360.f,-56.f,-120.f,-248.f,-36.f,-80.f,-168.f};
__constant__ float c_ay1[9] = {-40.f,-88.f,-184.f,-56.f,-120.f,-248.f,-80.f,-168.f,-344.f};
__constant__ float c_aw[9]  = {184.f,368.f,736.f,128.f,256.f,512.f,88.f,176.f,352.f};
__constant__ float c_ah[9]  = {96.f,192.f,384.f,128.f,256.f,512.f,176.f,352.f,704.f};

__device__ __forceinline__ u32 binof(u32 u) {
    if (u < 0x80000000u) return 0u;                               // -inf (invalid)
    if (u < 0xBF000000u) return 1u + ((u - 0x80000000u) >> 22);   // s<0.5 : 1..252
    return 256u + ((u - 0xBF000000u) >> 11);                      // s>=0.5: 256..4352
}

__device__ __forceinline__ bool iou_gt(float4 a, float areaA, float4 b, float areaB) {
    float ix1 = fmaxf(a.x, b.x), iy1 = fmaxf(a.y, b.y);
    float ix2 = fminf(a.z, b.z), iy2 = fminf(a.w, b.w);
    float iw = fmaxf(ix2 - ix1 + 1.0f, 0.0f);
    float ih = fmaxf(iy2 - iy1 + 1.0f, 0.0f);
    float inter = iw * ih;
    float iou = inter / (areaA + areaB - inter);
    return iou > 0.7f;
}

// ================= K1: proposal (r7 minus the histogram phase) ===============
__global__ __launch_bounds__(256) void proposal_kernel(const float* __restrict__ cls,
                                                       const float* __restrict__ dlt,
                                                       u64* __restrict__ keys,
                                                       float4* __restrict__ boxes) {
    const int t = threadIdx.x;
    int i = blockIdx.x * 256 + t;
    int a  = i % A_PER;
    int hw = i / A_PER;
    int wx = hw % WGRID;
    int hy = hw / WGRID;

    float2 lp = *(const float2*)(cls + hw * 18 + 2 * a);
    float l0 = lp.x, l1 = lp.y;
    float m  = fmaxf(l0, l1);
    float e0 = expf(l0 - m), e1 = expf(l1 - m);
    float s  = e1 / (e0 + e1);

    float4 dd = *(const float4*)(dlt + hw * 36 + 4 * a);
    float dx = dd.x, dy = dd.y, dw = dd.z, dh = dd.w;
    float aw = c_aw[a], ah = c_ah[a];
    float axc = (c_ax1[a] + 16.f * (float)wx) + 0.5f * aw;
    float ayc = (c_ay1[a] + 16.f * (float)hy) + 0.5f * ah;

    float pxc = dx * aw + axc;
    float pyc = dy * ah + ayc;
    float pw  = expf(dw) * aw;
    float phh = expf(dh) * ah;
    float x1 = pxc - 0.5f * pw, y1 = pyc - 0.5f * phh;
    float x2 = pxc + 0.5f * pw, y2 = pyc + 0.5f * phh;
    x1 = fminf(fmaxf(x1, 0.f), 1023.f);
    x2 = fminf(fmaxf(x2, 0.f), 1023.f);
    y1 = fminf(fmaxf(y1, 0.f), 1023.f);
    y2 = fminf(fmaxf(y2, 0.f), 1023.f);
    bool valid = ((x2 - x1 + 1.f) >= 16.f) && ((y2 - y1 + 1.f) >= 16.f);
    float sc = valid ? s : -__builtin_huge_valf();

    u32 sb  = __float_as_uint(sc);
    u32 ord = (sb & 0x80000000u) ? ~sb : (sb | 0x80000000u);
    u64 key = ((u64)ord << 32) | (u32)(~(u32)i);
    keys[i]  = key;
    boxes[i] = make_float4(x1, y1, x2, y2);
}

// ================= K2: fused selection (hist + scan + scatter + rank) ========
// ONE block, 1024 threads. Replaces memset + scan + scatter + rank kernels.
// Histogram/binStart/cursor/scat all in LDS (88 KB): after the scan reads lh,
// lh is reused as the scatter cursor; bucket count in rank is recovered as
// bst[b-1]-bst[b] (descending-scan identity end(b) = bst[b-1]).
__global__ __launch_bounds__(1024) void select_kernel(const u64* __restrict__ keys,
                                                      const float4* __restrict__ boxes,
                                                      u64* __restrict__ gscat,
                                                      float4* __restrict__ topBoxes,
                                                      u32* __restrict__ gEV) {
    __shared__ u32 lh[NBIN];        // pass1: counts; after scan: scatter cursors
    __shared__ u32 bst[NBIN];       // binStart (descending exclusive)
    __shared__ u64 scat[SCAP];      // bucketed keys (48 KB)
    __shared__ u32 wsum[16];
    __shared__ int sE;
    __shared__ int sV;
    const int t = threadIdx.x;
    const int lane = t & 63;
    const int v = t >> 6;
    for (int b = t; b < NBIN; b += 1024) lh[b] = 0;
    if (t == 0) { sV = KTOP; sE = KTOP; }
    __syncthreads();
    // ---- pass 1: histogram of key high-words
    for (int i = t; i < N_ANCH; i += 1024) {
        u32 hiw = (u32)(keys[i] >> 32);
        atomicAdd(&lh[binof(hiw)], 1u);
    }
    __syncthreads();
    // ---- descending exclusive scan, 5 bins per thread (verified r5 pattern)
    int hi = NBIN - 1 - 5 * t;      // thread t owns bins [hi-4 .. hi], descending
    u32 cnt[5];
    u32 sum = 0;
#pragma unroll
    for (int k = 0; k < 5; ++k) { cnt[k] = lh[hi - k]; sum += cnt[k]; }
    u32 s = sum;
#pragma unroll
    for (int d = 1; d < 64; d <<= 1) {
        u32 x = __shfl_up(s, d, 64);
        if (lane >= d) s += x;
    }
    if (lane == 63) wsum[v] = s;
    __syncthreads();                // also orders: all lh reads done before zeroing below
    u32 base = 0;
#pragma unroll
    for (int q = 0; q < 16; ++q) { u32 x = wsum[q]; if (q < v) base += x; }
    u32 run = base + s - sum;       // exclusive (sum of all higher bins)
#pragma unroll
    for (int k = 0; k < 5; ++k) {
        int b = hi - k;
        bst[b] = run;
        lh[b] = 0;                  // reuse as scatter cursor
        u32 end = run + cnt[k];
        if (run < KTOP && end >= KTOP) sE = (int)end;   // unique boundary bucket
        run = end;
    }
    __syncthreads();
    // ---- pass 2: scatter into contiguous per-bucket slots (LDS; global fallback)
    for (int i = t; i < N_ANCH; i += 1024) {
        u64 k = keys[i];
        u32 b = binof((u32)(k >> 32));
        u32 s0 = bst[b];
        if (s0 < KTOP) {
            u32 p = s0 + atomicAdd(&lh[b], 1u);
            if (p < SCAP) scat[p] = k; else gscat[p] = k;
        }
    }
    __syncthreads();                // __syncthreads drains vmcnt -> fallback writes visible
    // ---- exact rank within bucket (keys unique) + gather topBoxes
    const int E = sE;
    for (int i = t; i < E; i += 1024) {
        u64 k = (i < SCAP) ? scat[i] : gscat[i];
        u32 b = binof((u32)(k >> 32));
        u32 s0 = bst[b];
        u32 e0 = (b > 0) ? bst[b - 1] : (u32)N_ANCH;    // end(b) = bst[b-1]
        u32 r = s0;
        for (u32 j = s0; j < e0; ++j) {
            u64 kj = (j < SCAP) ? scat[j] : gscat[j];
            r += (kj > k) ? 1u : 0u;
        }
        if (r < KTOP) {
            int idx = (int)(~(u32)k);
            topBoxes[r] = boxes[idx];
            if (!(k >> 63)) atomicMin(&sV, (int)r);     // first -inf rank => V
        }
    }
    __syncthreads();
    if (t == 0) gEV[1] = (u32)sV;
}

// ================= K3: transposed mask via shfl (verified r6/r7) =============
// S[w][j] bit b = IoU(box_{64w+b}, box_j)>0.7 && 64w+b<j. Task=(jc,w), w<=jc.
__global__ __launch_bounds__(256) void maskT_kernel(const float4* __restrict__ topBoxes,
                                                    const u32* __restrict__ gEV,
                                                    u64* __restrict__ S) {
    const int V = (int)gEV[1];
    const int nch = (V + 63) >> 6;
    const int ntask = nch * (nch + 1) / 2;
    const int lane = threadIdx.x & 63;
    const int v = threadIdx.x >> 6;
    for (int tk = blockIdx.x * 4 + v; tk < ntask; tk += gridDim.x * 4) {
        int jc = (int)((sqrtf(8.f * (float)tk + 1.f) - 1.f) * 0.5f);
        while ((jc + 1) * (jc + 2) / 2 <= tk) ++jc;
        while (jc * (jc + 1) / 2 > tk) --jc;
        int w = tk - jc * (jc + 1) / 2;
        int ci = w * 64 + lane;
        float4 bi = (ci < V) ? topBoxes[ci] : make_float4(0.f, 0.f, -8.f, -8.f);
        float ai = (bi.z - bi.x + 1.f) * (bi.w - bi.y + 1.f);
        int j = jc * 64 + lane;
        float4 bj = (j < V) ? topBoxes[j] : make_float4(0.f, 0.f, -8.f, -8.f);
        float aj = (bj.z - bj.x + 1.f) * (bj.w - bj.y + 1.f);
        u64 m = 0;
#pragma unroll 4
        for (int b = 0; b < 64; ++b) {
            float4 bb;
            bb.x = __shfl(bi.x, b, 64); bb.y = __shfl(bi.y, b, 64);
            bb.z = __shfl(bi.z, b, 64); bb.w = __shfl(bi.w, b, 64);
            float ab = __shfl(ai, b, 64);
            if (iou_gt(bb, ab, bj, aj)) m |= (1ull << b);
        }
        if (w == jc) m &= ((1ull << lane) - 1ull);   // diag word: only i < j
        S[(u64)w * NJ + j] = m;
    }
}

// ---- NMS named-register slot machinery (rule #20: named scalars, not arrays).
#define SLOT_DECL(K) u64 kw##K = 0, pa##K = 0, pb##K = 0; u32 ao##K = 0;
#define SLOT_ACC(K)  if (nslot > 4*(K) + v) { accA |= pa##K & kw##K; accB |= pb##K & kw##K; }
#define SLOT_REF(K)  if (nslot > 4*(K) + v) { const u64* rp_ = S + (u64)ao##K * NJ + ofsn; pa##K = rp_[0]; pb##K = rp_[64]; }
#define SLOT_CASE(K) case K: kw##K = kb_; ao##K = wch_; if (pf_) { const u64* rp_ = S + (u64)wch_ * NJ + onx_; pa##K = rp_[0]; pb##K = rp_[64]; } break;
#define DO_CLAIM(KB, WCH) do {                                                \
    u64 kb_ = (KB); u32 wch_ = (WCH);                                         \
    int si_ = nslot >> 2, so_ = nslot & 3;                                    \
    if (si_ < NSLOT) {                                                        \
      if (v == so_) {                                                         \
        bool pf_ = (r + 1 < nr);                                              \
        u64 onx_ = (u64)(128 * (r + 1)) + lane;                               \
        switch (si_) {                                                        \
          SLOT_CASE(0) SLOT_CASE(1) SLOT_CASE(2) SLOT_CASE(3)                 \
          SLOT_CASE(4) SLOT_CASE(5) SLOT_CASE(6) SLOT_CASE(7)                 \
          SLOT_CASE(8) SLOT_CASE(9) SLOT_CASE(10) SLOT_CASE(11)               \
          default: break;                                                     \
        }                                                                     \
      }                                                                       \
      ++nslot;                                                                \
    } else if (nspill < SPILLCAP) {                                           \
      if (v == 3 && lane == 0) { spillW[nspill] = wch_; spillK[nspill] = kb_; } \
      ++nspill; sadd = true;                                                  \
    }                                                                         \
  } while (0)

// ================= K4: greedy NMS + output (verified r7, 1 block) ============
__global__ __launch_bounds__(256, 1) void nms_out_kernel(const float4* __restrict__ topBoxes,
                                                         const u32* __restrict__ gEV,
                                                         const u64* __restrict__ S,
                                                         float* __restrict__ out) {
    __shared__ u64 keepw[NCHK];
    __shared__ u64 supw[2][8];               // parity x (A:0..3 | B:4..7)
    __shared__ u64 spillK[SPILLCAP];
    __shared__ u32 spillW[SPILLCAP];
    __shared__ u32 wsum[4];
    const int t = threadIdx.x;
    const int lane = t & 63;
    const int v = t >> 6;                    // 4 waves
    const int V = (int)gEV[1];
    const int nch = (V + 63) >> 6;
    const int nr  = (nch + 1) >> 1;          // pair rounds
    if (t < NCHK) keepw[t] = 0;

    SLOT_DECL(0) SLOT_DECL(1) SLOT_DECL(2) SLOT_DECL(3)
    SLOT_DECL(4) SLOT_DECL(5) SLOT_DECL(6) SLOT_DECL(7)
    SLOT_DECL(8) SLOT_DECL(9) SLOT_DECL(10) SLOT_DECL(11)

    // diagonal words for round r, depth-1 prefetched (kept-independent addresses)
    u64 dAc  = S[lane];                      // S[0][0..63]
    u64 dABc = S[64 + lane];                 // S[0][64..127]
    u64 dBc  = S[(u64)NJ + 64 + lane];       // S[1][64..127]
    int nslot = 0, nspill = 0, nkept = 0;    // uniform & identical across waves

    for (int r = 0; r < nr; ++r) {
        const int par = r & 1;
        u64 accA = 0, accB = 0;
        SLOT_ACC(0) SLOT_ACC(1) SLOT_ACC(2) SLOT_ACC(3)
        SLOT_ACC(4) SLOT_ACC(5) SLOT_ACC(6) SLOT_ACC(7)
        SLOT_ACC(8) SLOT_ACC(9) SLOT_ACC(10) SLOT_ACC(11)
        for (int s2 = v; s2 < nspill; s2 += 4) {      // fallback (rarely active)
            u64 kk = spillK[s2];
            const u64* row = S + (u64)spillW[s2] * NJ + 128 * r + lane;
            accA |= row[0] & kk; accB |= row[64] & kk;
        }
        u64 bA = __ballot(accA != 0ull), bB = __ballot(accB != 0ull);
        if (lane == 0) { supw[par][v] = bA; supw[par][4 + v] = bB; }
        u64 dAn = 0, dABn = 0, dBn = 0;
        if (r + 1 < nr) {                    // refill prefetches for round r+1
            u64 ofsn = (u64)(128 * (r + 1)) + lane;
            SLOT_REF(0) SLOT_REF(1) SLOT_REF(2) SLOT_REF(3)
            SLOT_REF(4) SLOT_REF(5) SLOT_REF(6) SLOT_REF(7)
            SLOT_REF(8) SLOT_REF(9) SLOT_REF(10) SLOT_REF(11)
            int rn = r + 1;
            dAn  = S[(u64)(2 * rn) * NJ + 128 * rn + lane];
            dABn = S[(u64)(2 * rn) * NJ + 128 * rn + 64 + lane];
            dBn  = S[(u64)(2 * rn + 1) * NJ + 128 * rn + 64 + lane];
        }
        BARRIER_LDS();                       // the only barrier in the round
        u64 rwA = supw[par][0] | supw[par][1] | supw[par][2] | supw[par][3];
        u64 rwB = supw[par][4] | supw[par][5] | supw[par][6] | supw[par][7];
        int remA = V - 128 * r;
        int remB = remA - 64;
        u64 aliveA = (remA >= 64) ? ~0ull : ((remA <= 0) ? 0ull : ((1ull << remA) - 1ull));
        u64 aliveB = (remB >= 64) ? ~0ull : ((remB <= 0) ? 0ull : ((1ull << remB) - 1ull));
        u64 candA = ~rwA & aliveA, kbA = 0;
        while (candA) {
            int b = __builtin_ctzll(candA);
            kbA |= (1ull << b);
            candA &= ~(1ull << b);
            candA &= ~__ballot(((dAc >> b) & 1ull) != 0ull);
        }
        u64 supAB = __ballot((dABc & kbA) != 0ull);
        u64 candB = ~(rwB | supAB) & aliveB, kbB = 0;
        while (candB) {
            int b = __builtin_ctzll(candB);
            kbB |= (1ull << b);
            candB &= ~(1ull << b);
            candB &= ~__ballot(((dBc >> b) & 1ull) != 0ull);
        }
        if (t == 0) { keepw[2 * r] = kbA; if (2 * r + 1 < nch) keepw[2 * r + 1] = kbB; }
        bool sadd = false;
        if (kbA) DO_CLAIM(kbA, (u32)(2 * r));
        if (kbB) DO_CLAIM(kbB, (u32)(2 * r + 1));
        if (sadd) BARRIER_LDS();             // spill entries visible next round
        nkept += __popcll(kbA) + __popcll(kbB);
        dAc = dAn; dABc = dABn; dBc = dBn;
        if (nkept >= NOUT) break;            // uniform (kb identical per wave)
    }
    __syncthreads();

    // output: kept boxes in rank order, then not-kept (suppressed or rank>=V)
    // in rank order, filling up to 300 (verified semantics).
    const int per = 24;                      // 256*24 >= 6000
    int r0 = t * per;
    int r1 = min(r0 + per, KTOP);
    u32 cnt2 = 0;
    for (int rr = r0; rr < r1; ++rr)
        cnt2 += (u32)((keepw[rr >> 6] >> (rr & 63)) & 1ull);
    u32 s2 = cnt2;
#pragma unroll
    for (int d = 1; d < 64; d <<= 1) {
        u32 x = __shfl_up(s2, d, 64);
        if (lane >= d) s2 += x;
    }
    if (lane == 63) wsum[v] = s2;
    __syncthreads();
    u32 base = 0, total = 0;
#pragma unroll
    for (int q = 0; q < 4; ++q) {
        u32 x = wsum[q];
        if (q < v) base += x;
        total += x;
    }
    const int n1 = min((int)total, NOUT);
    int kp = (int)(base + s2 - cnt2);        // kept before r0
    for (int rr = r0; rr < r1; ++rr) {
        int kept = (int)((keepw[rr >> 6] >> (rr & 63)) & 1ull);
        int pos = kept ? kp : (n1 + rr - kp);
        if (pos < NOUT) {
            float4 b = topBoxes[rr];
            out[pos * 5 + 0] = 0.f;
            out[pos * 5 + 1] = b.x; out[pos * 5 + 2] = b.y;
            out[pos * 5 + 3] = b.z; out[pos * 5 + 4] = b.w;
        }
        kp += kept;
    }
}

extern "C" void kernel_launch(void* const* d_in, const int* in_sizes, int n_in,
                              void* d_out, int out_size, void* d_ws, size_t ws_size,
                              hipStream_t stream) {
    const float* cls = (const float*)d_in[0];   // (1,64,64,18) f32
    const float* dlt = (const float*)d_in[1];   // (1,64,64,36) f32
    float* out = (float*)d_out;                 // 300x5 f32
    char* ws = (char*)d_ws;
    u64*    keys     = (u64*)   (ws);                    // 294912
    u64*    gscat    = (u64*)   (ws + 294912);           // 294912 (select LDS-overflow)
    float4* boxes    = (float4*)(ws + 589824);           // 589824
    float4* topBoxes = (float4*)(ws + 1179648);          // 96000
    u32*    gEV      = (u32*)   (ws + 1337088);          // [1]=V
    u64*    S        = (u64*)   (ws + 1337344);          // 4524032 (94 x 6016 words)

    proposal_kernel<<<144, 256, 0, stream>>>(cls, dlt, keys, boxes);
    select_kernel<<<1, 1024, 0, stream>>>(keys, boxes, gscat, topBoxes, gEV);
    maskT_kernel<<<1120, 256, 0, stream>>>(topBoxes, gEV, S);
    nms_out_kernel<<<1, 256, 0, stream>>>(topBoxes, gEV, S, out);
}

// Round 9
// 134.616 us; speedup vs baseline: 1.0154x; 1.0154x over previous
//
#include <hip/hip_runtime.h>
#include <stdint.h>

typedef unsigned long long u64;
typedef unsigned int u32;

#define N_ANCH 36864
#define WGRID 64
#define A_PER 9
#define KTOP 6000
#define NOUT 300
#define NBIN 5120       // max used bin = 4352 (binof)
#define NCHK 94         // ceil(6000/64) = u64 words
#define NJ   6016       // padded j-stride of S (u64 words)
#define NSLOT 12        // named-register slots per wave (48 total; ~43 active expected)
#define SPILLCAP 64     // LDS overflow; 48+64 >= 94 chunks -> always correct
#define SCAP 6144       // LDS scat capacity (E ~ 6000; global fallback beyond)

// Raw barrier: LDS-drain only. Global prefetches stay in flight across it.
#define BARRIER_LDS() do {                                   \
    asm volatile("s_waitcnt lgkmcnt(0)" ::: "memory");       \
    __builtin_amdgcn_s_barrier();                            \
    asm volatile("" ::: "memory");                           \
} while (0)

// Base anchors from py-faster-rcnn generate_anchors (scales 8,16,32; ratios .5,1,2).
__constant__ float c_ax1[9] = {-84.f,-176.f,-360.f,-56.f,-120.f,-248.f,-36.f,-80.f,-168.f};
__constant__ float c_ay1[9] = {-40.f,-88.f,-184.f,-56.f,-120.f,-248.f,-80.f,-168.f,-344.f};
__constant__ float c_aw[9]  = {184.f,368.f,736.f,128.f,256.f,512.f,88.f,176.f,352.f};
__constant__ float c_ah[9]  = {96.f,192.f,384.f,128.f,256.f,512.f,176.f,352.f,704.f};

__device__ __forceinline__ u32 binof(u32 u) {
    if (u < 0x80000000u) return 0u;                               // -inf (invalid)
    if (u < 0xBF000000u) return 1u + ((u - 0x80000000u) >> 22);   // s<0.5 : 1..252
    return 256u + ((u - 0xBF000000u) >> 11);                      // s>=0.5: 256..4352
}

__device__ __forceinline__ bool iou_gt(float4 a, float areaA, float4 b, float areaB) {
    float ix1 = fmaxf(a.x, b.x), iy1 = fmaxf(a.y, b.y);
    float ix2 = fminf(a.z, b.z), iy2 = fminf(a.w, b.w);
    float iw = fmaxf(ix2 - ix1 + 1.0f, 0.0f);
    float ih = fmaxf(iy2 - iy1 + 1.0f, 0.0f);
    float inter = iw * ih;
    float iou = inter / (areaA + areaB - inter);
    return iou > 0.7f;
}

// ================= K1: proposal with distributed histogram (verified r7) =====
__global__ __launch_bounds__(256) void proposal_kernel(const float* __restrict__ cls,
                                                       const float* __restrict__ dlt,
                                                       u64* __restrict__ keys,
                                                       float4* __restrict__ boxes,
                                                       u32* __restrict__ hist) {
    __shared__ u32 lh[NBIN];
    const int t = threadIdx.x;
    const int lane = t & 63;
    for (int b = t; b < NBIN; b += 256) lh[b] = 0;
    __syncthreads();

    int i = blockIdx.x * 256 + t;
    int a  = i % A_PER;
    int hw = i / A_PER;
    int wx = hw % WGRID;
    int hy = hw / WGRID;

    float2 lp = *(const float2*)(cls + hw * 18 + 2 * a);
    float l0 = lp.x, l1 = lp.y;
    float m  = fmaxf(l0, l1);
    float e0 = expf(l0 - m), e1 = expf(l1 - m);
    float s  = e1 / (e0 + e1);

    float4 dd = *(const float4*)(dlt + hw * 36 + 4 * a);
    float dx = dd.x, dy = dd.y, dw = dd.z, dh = dd.w;
    float aw = c_aw[a], ah = c_ah[a];
    float axc = (c_ax1[a] + 16.f * (float)wx) + 0.5f * aw;
    float ayc = (c_ay1[a] + 16.f * (float)hy) + 0.5f * ah;

    float pxc = dx * aw + axc;
    float pyc = dy * ah + ayc;
    float pw  = expf(dw) * aw;
    float phh = expf(dh) * ah;
    float x1 = pxc - 0.5f * pw, y1 = pyc - 0.5f * phh;
    float x2 = pxc + 0.5f * pw, y2 = pyc + 0.5f * phh;
    x1 = fminf(fmaxf(x1, 0.f), 1023.f);
    x2 = fminf(fmaxf(x2, 0.f), 1023.f);
    y1 = fminf(fmaxf(y1, 0.f), 1023.f);
    y2 = fminf(fmaxf(y2, 0.f), 1023.f);
    bool valid = ((x2 - x1 + 1.f) >= 16.f) && ((y2 - y1 + 1.f) >= 16.f);
    float sc = valid ? s : -__builtin_huge_valf();

    u32 sb  = __float_as_uint(sc);
    u32 ord = (sb & 0x80000000u) ? ~sb : (sb | 0x80000000u);
    u64 key = ((u64)ord << 32) | (u32)(~(u32)i);
    keys[i]  = key;
    boxes[i] = make_float4(x1, y1, x2, y2);

    u64 infb = __ballot(!valid);
    if (valid) {
        atomicAdd(&lh[binof(ord)], 1u);
    } else {
        if (lane == __builtin_ctzll(infb))          // wave-aggregated -inf bin
            atomicAdd(&lh[0], (u32)__popcll(infb));
    }
    __syncthreads();
    for (int b = t; b < NBIN; b += 256) {
        u32 x = lh[b];
        if (x) atomicAdd(&hist[b], x);
    }
}

// ================= K2: fused scan + scatter + rank (r8-verified logic) =======
// ONE block, 1024 threads. Histogram comes from global (proposal), so no pass-1
// re-histogram and no bin-0 same-address contention (the r8 mistake). Cursors in
// LDS; scat in LDS (48 KB) with global fallback for E > SCAP (never taken here).
__global__ __launch_bounds__(1024) void select_kernel(const u32* __restrict__ hist,
                                                      const u64* __restrict__ keys,
                                                      const float4* __restrict__ boxes,
                                                      u64* __restrict__ gscat,
                                                      float4* __restrict__ topBoxes,
                                                      u32* __restrict__ gEV) {
    __shared__ u32 bst[NBIN];       // binStart (descending exclusive)
    __shared__ u32 cur[NBIN];       // scatter cursors
    __shared__ u64 scat[SCAP];      // bucketed keys (48 KB)
    __shared__ u32 wsum[16];
    __shared__ int sE;
    __shared__ int sV;
    const int t = threadIdx.x;
    const int lane = t & 63;
    const int v = t >> 6;
    if (t == 0) { sV = KTOP; sE = KTOP; }
    // ---- descending exclusive scan, 5 bins per thread (verified r5/r8 pattern)
    int hi = NBIN - 1 - 5 * t;      // thread t owns bins [hi-4 .. hi], descending
    u32 cnt[5];
    u32 sum = 0;
#pragma unroll
    for (int k = 0; k < 5; ++k) { cnt[k] = hist[hi - k]; sum += cnt[k]; }
    u32 s = sum;
#pragma unroll
    for (int d = 1; d < 64; d <<= 1) {
        u32 x = __shfl_up(s, d, 64);
        if (lane >= d) s += x;
    }
    if (lane == 63) wsum[v] = s;
    __syncthreads();
    u32 base = 0;
#pragma unroll
    for (int q = 0; q < 16; ++q) { u32 x = wsum[q]; if (q < v) base += x; }
    u32 run = base + s - sum;       // exclusive (sum of all higher bins)
#pragma unroll
    for (int k = 0; k < 5; ++k) {
        int b = hi - k;
        bst[b] = run;
        cur[b] = 0;
        u32 end = run + cnt[k];
        if (run < KTOP && end >= KTOP) sE = (int)end;   // unique boundary bucket
        run = end;
    }
    __syncthreads();
    // ---- scatter into contiguous per-bucket slots (LDS; global fallback)
    for (int i = t; i < N_ANCH; i += 1024) {
        u64 k = keys[i];
        u32 b = binof((u32)(k >> 32));
        u32 s0 = bst[b];
        if (s0 < KTOP) {
            u32 p = s0 + atomicAdd(&cur[b], 1u);
            if (p < SCAP) scat[p] = k; else gscat[p] = k;
        }
    }
    __syncthreads();                // drains vmcnt too -> fallback writes visible
    // ---- exact rank within bucket (keys unique) + gather topBoxes
    const int E = sE;
    for (int i = t; i < E; i += 1024) {
        u64 k = (i < SCAP) ? scat[i] : gscat[i];
        u32 b = binof((u32)(k >> 32));
        u32 s0 = bst[b];
        u32 e0 = (b > 0) ? bst[b - 1] : (u32)N_ANCH;    // end(b) = bst[b-1]
        u32 r = s0;
        for (u32 j = s0; j < e0; ++j) {
            u64 kj = (j < SCAP) ? scat[j] : gscat[j];
            r += (kj > k) ? 1u : 0u;
        }
        if (r < KTOP) {
            int idx = (int)(~(u32)k);
            topBoxes[r] = boxes[idx];
            if (!(k >> 63)) atomicMin(&sV, (int)r);     // first -inf rank => V
        }
    }
    __syncthreads();
    if (t == 0) gEV[1] = (u32)sV;
}

// ================= K3: transposed mask via shfl (verified r6/r7) =============
// S[w][j] bit b = IoU(box_{64w+b}, box_j)>0.7 && 64w+b<j. Task=(jc,w), w<=jc.
__global__ __launch_bounds__(256) void maskT_kernel(const float4* __restrict__ topBoxes,
                                                    const u32* __restrict__ gEV,
                                                    u64* __restrict__ S) {
    const int V = (int)gEV[1];
    const int nch = (V + 63) >> 6;
    const int ntask = nch * (nch + 1) / 2;
    const int lane = threadIdx.x & 63;
    const int v = threadIdx.x >> 6;
    for (int tk = blockIdx.x * 4 + v; tk < ntask; tk += gridDim.x * 4) {
        int jc = (int)((sqrtf(8.f * (float)tk + 1.f) - 1.f) * 0.5f);
        while ((jc + 1) * (jc + 2) / 2 <= tk) ++jc;
        while (jc * (jc + 1) / 2 > tk) --jc;
        int w = tk - jc * (jc + 1) / 2;
        int ci = w * 64 + lane;
        float4 bi = (ci < V) ? topBoxes[ci] : make_float4(0.f, 0.f, -8.f, -8.f);
        float ai = (bi.z - bi.x + 1.f) * (bi.w - bi.y + 1.f);
        int j = jc * 64 + lane;
        float4 bj = (j < V) ? topBoxes[j] : make_float4(0.f, 0.f, -8.f, -8.f);
        float aj = (bj.z - bj.x + 1.f) * (bj.w - bj.y + 1.f);
        u64 m = 0;
#pragma unroll 4
        for (int b = 0; b < 64; ++b) {
            float4 bb;
            bb.x = __shfl(bi.x, b, 64); bb.y = __shfl(bi.y, b, 64);
            bb.z = __shfl(bi.z, b, 64); bb.w = __shfl(bi.w, b, 64);
            float ab = __shfl(ai, b, 64);
            if (iou_gt(bb, ab, bj, aj)) m |= (1ull << b);
        }
        if (w == jc) m &= ((1ull << lane) - 1ull);   // diag word: only i < j
        S[(u64)w * NJ + j] = m;
    }
}

// ---- NMS named-register slot machinery (rule #20: named scalars, not arrays).
#define SLOT_DECL(K) u64 kw##K = 0, pa##K = 0, pb##K = 0; u32 ao##K = 0;
#define SLOT_ACC(K)  if (nslot > 4*(K) + v) { accA |= pa##K & kw##K; accB |= pb##K & kw##K; }
#define SLOT_REF(K)  if (nslot > 4*(K) + v) { const u64* rp_ = S + (u64)ao##K * NJ + ofsn; pa##K = rp_[0]; pb##K = rp_[64]; }
#define SLOT_CASE(K) case K: kw##K = kb_; ao##K = wch_; if (pf_) { const u64* rp_ = S + (u64)wch_ * NJ + onx_; pa##K = rp_[0]; pb##K = rp_[64]; } break;
#define DO_CLAIM(KB, WCH) do {                                                \
    u64 kb_ = (KB); u32 wch_ = (WCH);                                         \
    int si_ = nslot >> 2, so_ = nslot & 3;                                    \
    if (si_ < NSLOT) {                                                        \
      if (v == so_) {                                                         \
        bool pf_ = (r + 1 < nr);                                              \
        u64 onx_ = (u64)(128 * (r + 1)) + lane;                               \
        switch (si_) {                                                        \
          SLOT_CASE(0) SLOT_CASE(1) SLOT_CASE(2) SLOT_CASE(3)                 \
          SLOT_CASE(4) SLOT_CASE(5) SLOT_CASE(6) SLOT_CASE(7)                 \
          SLOT_CASE(8) SLOT_CASE(9) SLOT_CASE(10) SLOT_CASE(11)               \
          default: break;                                                     \
        }                                                                     \
      }                                                                       \
      ++nslot;                                                                \
    } else if (nspill < SPILLCAP) {                                           \
      if (v == 3 && lane == 0) { spillW[nspill] = wch_; spillK[nspill] = kb_; } \
      ++nspill; sadd = true;                                                  \
    }                                                                         \
  } while (0)

// ================= K4: greedy NMS + output (verified r7, byte-identical) =====
__global__ __launch_bounds__(256, 1) void nms_out_kernel(const float4* __restrict__ topBoxes,
                                                         const u32* __restrict__ gEV,
                                                         const u64* __restrict__ S,
                                                         float* __restrict__ out) {
    __shared__ u64 keepw[NCHK];
    __shared__ u64 supw[2][8];               // parity x (A:0..3 | B:4..7)
    __shared__ u64 spillK[SPILLCAP];
    __shared__ u32 spillW[SPILLCAP];
    __shared__ u32 wsum[4];
    const int t = threadIdx.x;
    const int lane = t & 63;
    const int v = t >> 6;                    // 4 waves
    const int V = (int)gEV[1];
    const int nch = (V + 63) >> 6;
    const int nr  = (nch + 1) >> 1;          // pair rounds
    if (t < NCHK) keepw[t] = 0;

    SLOT_DECL(0) SLOT_DECL(1) SLOT_DECL(2) SLOT_DECL(3)
    SLOT_DECL(4) SLOT_DECL(5) SLOT_DECL(6) SLOT_DECL(7)
    SLOT_DECL(8) SLOT_DECL(9) SLOT_DECL(10) SLOT_DECL(11)

    // diagonal words for round r, depth-1 prefetched (kept-independent addresses)
    u64 dAc  = S[lane];                      // S[0][0..63]
    u64 dABc = S[64 + lane];                 // S[0][64..127]
    u64 dBc  = S[(u64)NJ + 64 + lane];       // S[1][64..127]
    int nslot = 0, nspill = 0, nkept = 0;    // uniform & identical across waves

    for (int r = 0; r < nr; ++r) {
        const int par = r & 1;
        u64 accA = 0, accB = 0;
        SLOT_ACC(0) SLOT_ACC(1) SLOT_ACC(2) SLOT_ACC(3)
        SLOT_ACC(4) SLOT_ACC(5) SLOT_ACC(6) SLOT_ACC(7)
        SLOT_ACC(8) SLOT_ACC(9) SLOT_ACC(10) SLOT_ACC(11)
        for (int s2 = v; s2 < nspill; s2 += 4) {      // fallback (rarely active)
            u64 kk = spillK[s2];
            const u64* row = S + (u64)spillW[s2] * NJ + 128 * r + lane;
            accA |= row[0] & kk; accB |= row[64] & kk;
        }
        u64 bA = __ballot(accA != 0ull), bB = __ballot(accB != 0ull);
        if (lane == 0) { supw[par][v] = bA; supw[par][4 + v] = bB; }
        u64 dAn = 0, dABn = 0, dBn = 0;
        if (r + 1 < nr) {                    // refill prefetches for round r+1
            u64 ofsn = (u64)(128 * (r + 1)) + lane;
            SLOT_REF(0) SLOT_REF(1) SLOT_REF(2) SLOT_REF(3)
            SLOT_REF(4) SLOT_REF(5) SLOT_REF(6) SLOT_REF(7)
            SLOT_REF(8) SLOT_REF(9) SLOT_REF(10) SLOT_REF(11)
            int rn = r + 1;
            dAn  = S[(u64)(2 * rn) * NJ + 128 * rn + lane];
            dABn = S[(u64)(2 * rn) * NJ + 128 * rn + 64 + lane];
            dBn  = S[(u64)(2 * rn + 1) * NJ + 128 * rn + 64 + lane];
        }
        BARRIER_LDS();                       // the only barrier in the round
        u64 rwA = supw[par][0] | supw[par][1] | supw[par][2] | supw[par][3];
        u64 rwB = supw[par][4] | supw[par][5] | supw[par][6] | supw[par][7];
        int remA = V - 128 * r;
        int remB = remA - 64;
        u64 aliveA = (remA >= 64) ? ~0ull : ((remA <= 0) ? 0ull : ((1ull << remA) - 1ull));
        u64 aliveB = (remB >= 64) ? ~0ull : ((remB <= 0) ? 0ull : ((1ull << remB) - 1ull));
        u64 candA = ~rwA & aliveA, kbA = 0;
        while (candA) {
            int b = __builtin_ctzll(candA);
            kbA |= (1ull << b);
            candA &= ~(1ull << b);
            candA &= ~__ballot(((dAc >> b) & 1ull) != 0ull);
        }
        u64 supAB = __ballot((dABc & kbA) != 0ull);
        u64 candB = ~(rwB | supAB) & aliveB, kbB = 0;
        while (candB) {
            int b = __builtin_ctzll(candB);
            kbB |= (1ull << b);
            candB &= ~(1ull << b);
            candB &= ~__ballot(((dBc >> b) & 1ull) != 0ull);
        }
        if (t == 0) { keepw[2 * r] = kbA; if (2 * r + 1 < nch) keepw[2 * r + 1] = kbB; }
        bool sadd = false;
        if (kbA) DO_CLAIM(kbA, (u32)(2 * r));
        if (kbB) DO_CLAIM(kbB, (u32)(2 * r + 1));
        if (sadd) BARRIER_LDS();             // spill entries visible next round
        nkept += __popcll(kbA) + __popcll(kbB);
        dAc = dAn; dABc = dABn; dBc = dBn;
        if (nkept >= NOUT) break;            // uniform (kb identical per wave)
    }
    __syncthreads();

    // output: kept boxes in rank order, then not-kept (suppressed or rank>=V)
    // in rank order, filling up to 300 (verified semantics).
    const int per = 24;                      // 256*24 >= 6000
    int r0 = t * per;
    int r1 = min(r0 + per, KTOP);
    u32 cnt2 = 0;
    for (int rr = r0; rr < r1; ++rr)
        cnt2 += (u32)((keepw[rr >> 6] >> (rr & 63)) & 1ull);
    u32 s2 = cnt2;
#pragma unroll
    for (int d = 1; d < 64; d <<= 1) {
        u32 x = __shfl_up(s2, d, 64);
        if (lane >= d) s2 += x;
    }
    if (lane == 63) wsum[v] = s2;
    __syncthreads();
    u32 base = 0, total = 0;
#pragma unroll
    for (int q = 0; q < 4; ++q) {
        u32 x = wsum[q];
        if (q < v) base += x;
        total += x;
    }
    const int n1 = min((int)total, NOUT);
    int kp = (int)(base + s2 - cnt2);        // kept before r0
    for (int rr = r0; rr < r1; ++rr) {
        int kept = (int)((keepw[rr >> 6] >> (rr & 63)) & 1ull);
        int pos = kept ? kp : (n1 + rr - kp);
        if (pos < NOUT) {
            float4 b = topBoxes[rr];
            out[pos * 5 + 0] = 0.f;
            out[pos * 5 + 1] = b.x; out[pos * 5 + 2] = b.y;
            out[pos * 5 + 3] = b.z; out[pos * 5 + 4] = b.w;
        }
        kp += kept;
    }
}

extern "C" void kernel_launch(void* const* d_in, const int* in_sizes, int n_in,
                              void* d_out, int out_size, void* d_ws, size_t ws_size,
                              hipStream_t stream) {
    const float* cls = (const float*)d_in[0];   // (1,64,64,18) f32
    const float* dlt = (const float*)d_in[1];   // (1,64,64,36) f32
    float* out = (float*)d_out;                 // 300x5 f32
    char* ws = (char*)d_ws;
    u64*    keys     = (u64*)   (ws);                    // 294912
    u64*    gscat    = (u64*)   (ws + 294912);           // 294912 (select LDS-overflow)
    float4* boxes    = (float4*)(ws + 589824);           // 589824
    float4* topBoxes = (float4*)(ws + 1179648);          // 96000
    u32*    hist     = (u32*)   (ws + 1275648);          // 20480
    u32*    gEV      = (u32*)   (ws + 1337088);          // [1]=V
    u64*    S        = (u64*)   (ws + 1337344);          // 4524032 (94 x 6016 words)

    hipMemsetAsync(hist, 0, NBIN * sizeof(u32), stream);     // hist only (cursors in LDS)
    proposal_kernel<<<144, 256, 0, stream>>>(cls, dlt, keys, boxes, hist);
    select_kernel<<<1, 1024, 0, stream>>>(hist, keys, boxes, gscat, topBoxes, gEV);
    maskT_kernel<<<1120, 256, 0, stream>>>(topBoxes, gEV, S);
    nms_out_kernel<<<1, 256, 0, stream>>>(topBoxes, gEV, S, out);
}

// Round 10
// 126.497 us; speedup vs baseline: 1.0806x; 1.0642x over previous
//
#include <hip/hip_runtime.h>
#include <stdint.h>

typedef unsigned long long u64;
typedef unsigned int u32;

#define N_ANCH 36864
#define WGRID 64
#define A_PER 9
#define KTOP 6000
#define NOUT 300
#define NBIN 5120       // max used bin = 4352 (binof)
#define NCHK 94         // ceil(6000/64) = u64 words
#define NJ   6016       // padded j-stride of S (u64 words)
#define NSLOT 12        // named-register slots per wave (48 total; ~43 active expected)
#define SPILLCAP 64     // LDS overflow; 48+64 >= 94 chunks -> always correct
#define SCAP 6144       // LDS scat capacity (E ~ 6000; global fallback beyond)
#define KPT 18          // ulonglong2 key loads per thread in select (36 keys)

// Raw barrier: LDS-drain only. Global prefetches stay in flight across it.
#define BARRIER_LDS() do {                                   \
    asm volatile("s_waitcnt lgkmcnt(0)" ::: "memory");       \
    __builtin_amdgcn_s_barrier();                            \
    asm volatile("" ::: "memory");                           \
} while (0)

// Base anchors from py-faster-rcnn generate_anchors (scales 8,16,32; ratios .5,1,2).
__constant__ float c_ax1[9] = {-84.f,-176.f,-360.f,-56.f,-120.f,-248.f,-36.f,-80.f,-168.f};
__constant__ float c_ay1[9] = {-40.f,-88.f,-184.f,-56.f,-120.f,-248.f,-80.f,-168.f,-344.f};
__constant__ float c_aw[9]  = {184.f,368.f,736.f,128.f,256.f,512.f,88.f,176.f,352.f};
__constant__ float c_ah[9]  = {96.f,192.f,384.f,128.f,256.f,512.f,176.f,352.f,704.f};

__device__ __forceinline__ u32 binof(u32 u) {
    if (u < 0x80000000u) return 0u;                               // -inf (invalid)
    if (u < 0xBF000000u) return 1u + ((u - 0x80000000u) >> 22);   // s<0.5 : 1..252
    return 256u + ((u - 0xBF000000u) >> 11);                      // s>=0.5: 256..4352
}

__device__ __forceinline__ bool iou_gt(float4 a, float areaA, float4 b, float areaB) {
    float ix1 = fmaxf(a.x, b.x), iy1 = fmaxf(a.y, b.y);
    float ix2 = fminf(a.z, b.z), iy2 = fminf(a.w, b.w);
    float iw = fmaxf(ix2 - ix1 + 1.0f, 0.0f);
    float ih = fmaxf(iy2 - iy1 + 1.0f, 0.0f);
    float inter = iw * ih;
    float iou = inter / (areaA + areaB - inter);
    return iou > 0.7f;
}

// ================= K1: proposal with distributed histogram (verified r7) =====
__global__ __launch_bounds__(256) void proposal_kernel(const float* __restrict__ cls,
                                                       const float* __restrict__ dlt,
                                                       u64* __restrict__ keys,
                                                       float4* __restrict__ boxes,
                                                       u32* __restrict__ hist) {
    __shared__ u32 lh[NBIN];
    const int t = threadIdx.x;
    const int lane = t & 63;
    for (int b = t; b < NBIN; b += 256) lh[b] = 0;
    __syncthreads();

    int i = blockIdx.x * 256 + t;
    int a  = i % A_PER;
    int hw = i / A_PER;
    int wx = hw % WGRID;
    int hy = hw / WGRID;

    float2 lp = *(const float2*)(cls + hw * 18 + 2 * a);
    float l0 = lp.x, l1 = lp.y;
    float m  = fmaxf(l0, l1);
    float e0 = expf(l0 - m), e1 = expf(l1 - m);
    float s  = e1 / (e0 + e1);

    float4 dd = *(const float4*)(dlt + hw * 36 + 4 * a);
    float dx = dd.x, dy = dd.y, dw = dd.z, dh = dd.w;
    float aw = c_aw[a], ah = c_ah[a];
    float axc = (c_ax1[a] + 16.f * (float)wx) + 0.5f * aw;
    float ayc = (c_ay1[a] + 16.f * (float)hy) + 0.5f * ah;

    float pxc = dx * aw + axc;
    float pyc = dy * ah + ayc;
    float pw  = expf(dw) * aw;
    float phh = expf(dh) * ah;
    float x1 = pxc - 0.5f * pw, y1 = pyc - 0.5f * phh;
    float x2 = pxc + 0.5f * pw, y2 = pyc + 0.5f * phh;
    x1 = fminf(fmaxf(x1, 0.f), 1023.f);
    x2 = fminf(fmaxf(x2, 0.f), 1023.f);
    y1 = fminf(fmaxf(y1, 0.f), 1023.f);
    y2 = fminf(fmaxf(y2, 0.f), 1023.f);
    bool valid = ((x2 - x1 + 1.f) >= 16.f) && ((y2 - y1 + 1.f) >= 16.f);
    float sc = valid ? s : -__builtin_huge_valf();

    u32 sb  = __float_as_uint(sc);
    u32 ord = (sb & 0x80000000u) ? ~sb : (sb | 0x80000000u);
    u64 key = ((u64)ord << 32) | (u32)(~(u32)i);
    keys[i]  = key;
    boxes[i] = make_float4(x1, y1, x2, y2);

    u64 infb = __ballot(!valid);
    if (valid) {
        atomicAdd(&lh[binof(ord)], 1u);
    } else {
        if (lane == __builtin_ctzll(infb))          // wave-aggregated -inf bin
            atomicAdd(&lh[0], (u32)__popcll(infb));
    }
    __syncthreads();
    for (int b = t; b < NBIN; b += 256) {
        u32 x = lh[b];
        if (x) atomicAdd(&hist[b], x);
    }
}

// ================= K2: fused scan + scatter + rank (r9 logic, pipelined read) =
// ONE block, 1024 threads. r8/r9 post-mortem: the single-CU COLD REMOTE key read
// was ~25 us at compiler-default concurrency. Fix: load all 36 keys/thread as
// 18x ulonglong2 into statically-indexed registers BEFORE processing (16 waves x
// 18 KB in flight covers ~700cy remote latency), then scatter from registers.
__global__ __launch_bounds__(1024) void select_kernel(const u32* __restrict__ hist,
                                                      const u64* __restrict__ keys,
                                                      const float4* __restrict__ boxes,
                                                      u64* __restrict__ gscat,
                                                      float4* __restrict__ topBoxes,
                                                      u32* __restrict__ gEV) {
    __shared__ u32 bst[NBIN];       // binStart (descending exclusive)
    __shared__ u32 cur[NBIN];       // scatter cursors
    __shared__ u64 scat[SCAP];      // bucketed keys (48 KB)
    __shared__ u32 wsum[16];
    __shared__ int sE;
    __shared__ int sV;
    const int t = threadIdx.x;
    const int lane = t & 63;
    const int v = t >> 6;
    if (t == 0) { sV = KTOP; sE = KTOP; }
    // ---- issue the full key stream early (coalesced 16B, static indices -> regs)
    ulonglong2 kb[KPT];
#pragma unroll
    for (int q = 0; q < KPT; ++q)
        kb[q] = *(const ulonglong2*)(keys + 2 * (q * 1024 + t));
    // ---- descending exclusive scan, 5 bins per thread (verified r5/r9 pattern)
    int hi = NBIN - 1 - 5 * t;      // thread t owns bins [hi-4 .. hi], descending
    u32 cnt[5];
    u32 sum = 0;
#pragma unroll
    for (int k = 0; k < 5; ++k) { cnt[k] = hist[hi - k]; sum += cnt[k]; }
    u32 s = sum;
#pragma unroll
    for (int d = 1; d < 64; d <<= 1) {
        u32 x = __shfl_up(s, d, 64);
        if (lane >= d) s += x;
    }
    if (lane == 63) wsum[v] = s;
    __syncthreads();
    u32 base = 0;
#pragma unroll
    for (int q = 0; q < 16; ++q) { u32 x = wsum[q]; if (q < v) base += x; }
    u32 run = base + s - sum;       // exclusive (sum of all higher bins)
#pragma unroll
    for (int k = 0; k < 5; ++k) {
        int b = hi - k;
        bst[b] = run;
        cur[b] = 0;
        u32 end = run + cnt[k];
        if (run < KTOP && end >= KTOP) sE = (int)end;   // unique boundary bucket
        run = end;
    }
    __syncthreads();
    // ---- scatter from registers into contiguous per-bucket slots
#pragma unroll
    for (int q = 0; q < KPT; ++q) {
#pragma unroll
        for (int h = 0; h < 2; ++h) {
            u64 k = h ? kb[q].y : kb[q].x;
            u32 b = binof((u32)(k >> 32));
            u32 s0 = bst[b];
            if (s0 < KTOP) {
                u32 p = s0 + atomicAdd(&cur[b], 1u);
                if (p < SCAP) scat[p] = k; else gscat[p] = k;
            }
        }
    }
    __syncthreads();                // drains vmcnt too -> fallback writes visible
    // ---- exact rank within bucket (keys unique) + gather topBoxes
    const int E = sE;
    for (int i = t; i < E; i += 1024) {
        u64 k = (i < SCAP) ? scat[i] : gscat[i];
        u32 b = binof((u32)(k >> 32));
        u32 s0 = bst[b];
        u32 e0 = (b > 0) ? bst[b - 1] : (u32)N_ANCH;    // end(b) = bst[b-1]
        u32 r = s0;
        for (u32 j = s0; j < e0; ++j) {
            u64 kj = (j < SCAP) ? scat[j] : gscat[j];
            r += (kj > k) ? 1u : 0u;
        }
        if (r < KTOP) {
            int idx = (int)(~(u32)k);
            topBoxes[r] = boxes[idx];
            if (!(k >> 63)) atomicMin(&sV, (int)r);     // first -inf rank => V
        }
    }
    __syncthreads();
    if (t == 0) gEV[1] = (u32)sV;
}

// ================= K3: transposed mask via shfl (verified r6/r7) =============
// S[w][j] bit b = IoU(box_{64w+b}, box_j)>0.7 && 64w+b<j. Task=(jc,w), w<=jc.
__global__ __launch_bounds__(256) void maskT_kernel(const float4* __restrict__ topBoxes,
                                                    const u32* __restrict__ gEV,
                                                    u64* __restrict__ S) {
    const int V = (int)gEV[1];
    const int nch = (V + 63) >> 6;
    const int ntask = nch * (nch + 1) / 2;
    const int lane = threadIdx.x & 63;
    const int v = threadIdx.x >> 6;
    for (int tk = blockIdx.x * 4 + v; tk < ntask; tk += gridDim.x * 4) {
        int jc = (int)((sqrtf(8.f * (float)tk + 1.f) - 1.f) * 0.5f);
        while ((jc + 1) * (jc + 2) / 2 <= tk) ++jc;
        while (jc * (jc + 1) / 2 > tk) --jc;
        int w = tk - jc * (jc + 1) / 2;
        int ci = w * 64 + lane;
        float4 bi = (ci < V) ? topBoxes[ci] : make_float4(0.f, 0.f, -8.f, -8.f);
        float ai = (bi.z - bi.x + 1.f) * (bi.w - bi.y + 1.f);
        int j = jc * 64 + lane;
        float4 bj = (j < V) ? topBoxes[j] : make_float4(0.f, 0.f, -8.f, -8.f);
        float aj = (bj.z - bj.x + 1.f) * (bj.w - bj.y + 1.f);
        u64 m = 0;
#pragma unroll 4
        for (int b = 0; b < 64; ++b) {
            float4 bb;
            bb.x = __shfl(bi.x, b, 64); bb.y = __shfl(bi.y, b, 64);
            bb.z = __shfl(bi.z, b, 64); bb.w = __shfl(bi.w, b, 64);
            float ab = __shfl(ai, b, 64);
            if (iou_gt(bb, ab, bj, aj)) m |= (1ull << b);
        }
        if (w == jc) m &= ((1ull << lane) - 1ull);   // diag word: only i < j
        S[(u64)w * NJ + j] = m;
    }
}

// ---- NMS named-register slot machinery (rule #20: named scalars, not arrays).
#define SLOT_DECL(K) u64 kw##K = 0, pa##K = 0, pb##K = 0; u32 ao##K = 0;
#define SLOT_ACC(K)  if (nslot > 4*(K) + v) { accA |= pa##K & kw##K; accB |= pb##K & kw##K; }
#define SLOT_REF(K)  if (nslot > 4*(K) + v) { const u64* rp_ = S + (u64)ao##K * NJ + ofsn; pa##K = rp_[0]; pb##K = rp_[64]; }
#define SLOT_CASE(K) case K: kw##K = kb_; ao##K = wch_; if (pf_) { const u64* rp_ = S + (u64)wch_ * NJ + onx_; pa##K = rp_[0]; pb##K = rp_[64]; } break;
#define DO_CLAIM(KB, WCH) do {                                                \
    u64 kb_ = (KB); u32 wch_ = (WCH);                                         \
    int si_ = nslot >> 2, so_ = nslot & 3;                                    \
    if (si_ < NSLOT) {                                                        \
      if (v == so_) {                                                         \
        bool pf_ = (r + 1 < nr);                                              \
        u64 onx_ = (u64)(128 * (r + 1)) + lane;                               \
        switch (si_) {                                                        \
          SLOT_CASE(0) SLOT_CASE(1) SLOT_CASE(2) SLOT_CASE(3)                 \
          SLOT_CASE(4) SLOT_CASE(5) SLOT_CASE(6) SLOT_CASE(7)                 \
          SLOT_CASE(8) SLOT_CASE(9) SLOT_CASE(10) SLOT_CASE(11)               \
          default: break;                                                     \
        }                                                                     \
      }                                                                       \
      ++nslot;                                                                \
    } else if (nspill < SPILLCAP) {                                           \
      if (v == 3 && lane == 0) { spillW[nspill] = wch_; spillK[nspill] = kb_; } \
      ++nspill; sadd = true;                                                  \
    }                                                                         \
  } while (0)

// ================= K4: greedy NMS + output (verified r7, byte-identical) =====
__global__ __launch_bounds__(256, 1) void nms_out_kernel(const float4* __restrict__ topBoxes,
                                                         const u32* __restrict__ gEV,
                                                         const u64* __restrict__ S,
                                                         float* __restrict__ out) {
    __shared__ u64 keepw[NCHK];
    __shared__ u64 supw[2][8];               // parity x (A:0..3 | B:4..7)
    __shared__ u64 spillK[SPILLCAP];
    __shared__ u32 spillW[SPILLCAP];
    __shared__ u32 wsum[4];
    const int t = threadIdx.x;
    const int lane = t & 63;
    const int v = t >> 6;                    // 4 waves
    const int V = (int)gEV[1];
    const int nch = (V + 63) >> 6;
    const int nr  = (nch + 1) >> 1;          // pair rounds
    if (t < NCHK) keepw[t] = 0;

    SLOT_DECL(0) SLOT_DECL(1) SLOT_DECL(2) SLOT_DECL(3)
    SLOT_DECL(4) SLOT_DECL(5) SLOT_DECL(6) SLOT_DECL(7)
    SLOT_DECL(8) SLOT_DECL(9) SLOT_DECL(10) SLOT_DECL(11)

    // diagonal words for round r, depth-1 prefetched (kept-independent addresses)
    u64 dAc  = S[lane];                      // S[0][0..63]
    u64 dABc = S[64 + lane];                 // S[0][64..127]
    u64 dBc  = S[(u64)NJ + 64 + lane];       // S[1][64..127]
    int nslot = 0, nspill = 0, nkept = 0;    // uniform & identical across waves

    for (int r = 0; r < nr; ++r) {
        const int par = r & 1;
        u64 accA = 0, accB = 0;
        SLOT_ACC(0) SLOT_ACC(1) SLOT_ACC(2) SLOT_ACC(3)
        SLOT_ACC(4) SLOT_ACC(5) SLOT_ACC(6) SLOT_ACC(7)
        SLOT_ACC(8) SLOT_ACC(9) SLOT_ACC(10) SLOT_ACC(11)
        for (int s2 = v; s2 < nspill; s2 += 4) {      // fallback (rarely active)
            u64 kk = spillK[s2];
            const u64* row = S + (u64)spillW[s2] * NJ + 128 * r + lane;
            accA |= row[0] & kk; accB |= row[64] & kk;
        }
        u64 bA = __ballot(accA != 0ull), bB = __ballot(accB != 0ull);
        if (lane == 0) { supw[par][v] = bA; supw[par][4 + v] = bB; }
        u64 dAn = 0, dABn = 0, dBn = 0;
        if (r + 1 < nr) {                    // refill prefetches for round r+1
            u64 ofsn = (u64)(128 * (r + 1)) + lane;
            SLOT_REF(0) SLOT_REF(1) SLOT_REF(2) SLOT_REF(3)
            SLOT_REF(4) SLOT_REF(5) SLOT_REF(6) SLOT_REF(7)
            SLOT_REF(8) SLOT_REF(9) SLOT_REF(10) SLOT_REF(11)
            int rn = r + 1;
            dAn  = S[(u64)(2 * rn) * NJ + 128 * rn + lane];
            dABn = S[(u64)(2 * rn) * NJ + 128 * rn + 64 + lane];
            dBn  = S[(u64)(2 * rn + 1) * NJ + 128 * rn + 64 + lane];
        }
        BARRIER_LDS();                       // the only barrier in the round
        u64 rwA = supw[par][0] | supw[par][1] | supw[par][2] | supw[par][3];
        u64 rwB = supw[par][4] | supw[par][5] | supw[par][6] | supw[par][7];
        int remA = V - 128 * r;
        int remB = remA - 64;
        u64 aliveA = (remA >= 64) ? ~0ull : ((remA <= 0) ? 0ull : ((1ull << remA) - 1ull));
        u64 aliveB = (remB >= 64) ? ~0ull : ((remB <= 0) ? 0ull : ((1ull << remB) - 1ull));
        u64 candA = ~rwA & aliveA, kbA = 0;
        while (candA) {
            int b = __builtin_ctzll(candA);
            kbA |= (1ull << b);
            candA &= ~(1ull << b);
            candA &= ~__ballot(((dAc >> b) & 1ull) != 0ull);
        }
        u64 supAB = __ballot((dABc & kbA) != 0ull);
        u64 candB = ~(rwB | supAB) & aliveB, kbB = 0;
        while (candB) {
            int b = __builtin_ctzll(candB);
            kbB |= (1ull << b);
            candB &= ~(1ull << b);
            candB &= ~__ballot(((dBc >> b) & 1ull) != 0ull);
        }
        if (t == 0) { keepw[2 * r] = kbA; if (2 * r + 1 < nch) keepw[2 * r + 1] = kbB; }
        bool sadd = false;
        if (kbA) DO_CLAIM(kbA, (u32)(2 * r));
        if (kbB) DO_CLAIM(kbB, (u32)(2 * r + 1));
        if (sadd) BARRIER_LDS();             // spill entries visible next round
        nkept += __popcll(kbA) + __popcll(kbB);
        dAc = dAn; dABc = dABn; dBc = dBn;
        if (nkept >= NOUT) break;            // uniform (kb identical per wave)
    }
    __syncthreads();

    // output: kept boxes in rank order, then not-kept (suppressed or rank>=V)
    // in rank order, filling up to 300 (verified semantics).
    const int per = 24;                      // 256*24 >= 6000
    int r0 = t * per;
    int r1 = min(r0 + per, KTOP);
    u32 cnt2 = 0;
    for (int rr = r0; rr < r1; ++rr)
        cnt2 += (u32)((keepw[rr >> 6] >> (rr & 63)) & 1ull);
    u32 s2 = cnt2;
#pragma unroll
    for (int d = 1; d < 64; d <<= 1) {
        u32 x = __shfl_up(s2, d, 64);
        if (lane >= d) s2 += x;
    }
    if (lane == 63) wsum[v] = s2;
    __syncthreads();
    u32 base = 0, total = 0;
#pragma unroll
    for (int q = 0; q < 4; ++q) {
        u32 x = wsum[q];
        if (q < v) base += x;
        total += x;
    }
    const int n1 = min((int)total, NOUT);
    int kp = (int)(base + s2 - cnt2);        // kept before r0
    for (int rr = r0; rr < r1; ++rr) {
        int kept = (int)((keepw[rr >> 6] >> (rr & 63)) & 1ull);
        int pos = kept ? kp : (n1 + rr - kp);
        if (pos < NOUT) {
            float4 b = topBoxes[rr];
            out[pos * 5 + 0] = 0.f;
            out[pos * 5 + 1] = b.x; out[pos * 5 + 2] = b.y;
            out[pos * 5 + 3] = b.z; out[pos * 5 + 4] = b.w;
        }
        kp += kept;
    }
}

extern "C" void kernel_launch(void* const* d_in, const int* in_sizes, int n_in,
                              void* d_out, int out_size, void* d_ws, size_t ws_size,
                              hipStream_t stream) {
    const float* cls = (const float*)d_in[0];   // (1,64,64,18) f32
    const float* dlt = (const float*)d_in[1];   // (1,64,64,36) f32
    float* out = (float*)d_out;                 // 300x5 f32
    char* ws = (char*)d_ws;
    u64*    keys     = (u64*)   (ws);                    // 294912
    u64*    gscat    = (u64*)   (ws + 294912);           // 294912 (select LDS-overflow)
    float4* boxes    = (float4*)(ws + 589824);           // 589824
    float4* topBoxes = (float4*)(ws + 1179648);          // 96000
    u32*    hist     = (u32*)   (ws + 1275648);          // 20480
    u32*    gEV      = (u32*)   (ws + 1337088);          // [1]=V
    u64*    S        = (u64*)   (ws + 1337344);          // 4524032 (94 x 6016 words)

    hipMemsetAsync(hist, 0, NBIN * sizeof(u32), stream);     // hist only (cursors in LDS)
    proposal_kernel<<<144, 256, 0, stream>>>(cls, dlt, keys, boxes, hist);
    select_kernel<<<1, 1024, 0, stream>>>(hist, keys, boxes, gscat, topBoxes, gEV);
    maskT_kernel<<<1120, 256, 0, stream>>>(topBoxes, gEV, S);
    nms_out_kernel<<<1, 256, 0, stream>>>(topBoxes, gEV, S, out);
}

// Round 11
// 114.736 us; speedup vs baseline: 1.1913x; 1.1025x over previous
//
#include <hip/hip_runtime.h>
#include <stdint.h>

typedef unsigned long long u64;
typedef unsigned int u32;

#define N_ANCH 36864
#define WGRID 64
#define A_PER 9
#define KTOP 6000
#define NOUT 300
#define NBIN 5120       // max used bin = 4352 (binof)
#define NCHK 94         // ceil(6000/64) = u64 words
#define NJ   6016       // padded j-stride of S (u64 words)
#define NSLOT 12        // named-register slots per wave (48 total; ~43 active expected)
#define SPILLCAP 64     // LDS overflow; 48+64 >= 94 chunks -> always correct

// Raw barrier: LDS-drain only. Global loads stay in flight across it.
#define BARRIER_LDS() do {                                   \
    asm volatile("s_waitcnt lgkmcnt(0)" ::: "memory");       \
    __builtin_amdgcn_s_barrier();                            \
    asm volatile("" ::: "memory");                           \
} while (0)

// Base anchors from py-faster-rcnn generate_anchors (scales 8,16,32; ratios .5,1,2).
__constant__ float c_ax1[9] = {-84.f,-176.f,-360.f,-56.f,-120.f,-248.f,-36.f,-80.f,-168.f};
__constant__ float c_ay1[9] = {-40.f,-88.f,-184.f,-56.f,-120.f,-248.f,-80.f,-168.f,-344.f};
__constant__ float c_aw[9]  = {184.f,368.f,736.f,128.f,256.f,512.f,88.f,176.f,352.f};
__constant__ float c_ah[9]  = {96.f,192.f,384.f,128.f,256.f,512.f,176.f,352.f,704.f};

__device__ __forceinline__ u32 binof(u32 u) {
    if (u < 0x80000000u) return 0u;                               // -inf (invalid)
    if (u < 0xBF000000u) return 1u + ((u - 0x80000000u) >> 22);   // s<0.5 : 1..252
    return 256u + ((u - 0xBF000000u) >> 11);                      // s>=0.5: 256..4352
}

__device__ __forceinline__ bool iou_gt(float4 a, float areaA, float4 b, float areaB) {
    float ix1 = fmaxf(a.x, b.x), iy1 = fmaxf(a.y, b.y);
    float ix2 = fminf(a.z, b.z), iy2 = fminf(a.w, b.w);
    float iw = fmaxf(ix2 - ix1 + 1.0f, 0.0f);
    float ih = fmaxf(iy2 - iy1 + 1.0f, 0.0f);
    float inter = iw * ih;
    float iou = inter / (areaA + areaB - inter);
    return iou > 0.7f;
}

// ================= K1: proposal (verified r6/r7) =============================
__global__ __launch_bounds__(256) void proposal_kernel(const float* __restrict__ cls,
                                                       const float* __restrict__ dlt,
                                                       u64* __restrict__ keys,
                                                       float4* __restrict__ boxes,
                                                       u32* __restrict__ hist) {
    __shared__ u32 lh[NBIN];
    const int t = threadIdx.x;
    const int lane = t & 63;
    for (int b = t; b < NBIN; b += 256) lh[b] = 0;
    __syncthreads();

    int i = blockIdx.x * 256 + t;
    int a  = i % A_PER;
    int hw = i / A_PER;
    int wx = hw % WGRID;
    int hy = hw / WGRID;

    float2 lp = *(const float2*)(cls + hw * 18 + 2 * a);
    float l0 = lp.x, l1 = lp.y;
    float m  = fmaxf(l0, l1);
    float e0 = expf(l0 - m), e1 = expf(l1 - m);
    float s  = e1 / (e0 + e1);

    float4 dd = *(const float4*)(dlt + hw * 36 + 4 * a);
    float dx = dd.x, dy = dd.y, dw = dd.z, dh = dd.w;
    float aw = c_aw[a], ah = c_ah[a];
    float axc = (c_ax1[a] + 16.f * (float)wx) + 0.5f * aw;
    float ayc = (c_ay1[a] + 16.f * (float)hy) + 0.5f * ah;

    float pxc = dx * aw + axc;
    float pyc = dy * ah + ayc;
    float pw  = expf(dw) * aw;
    float phh = expf(dh) * ah;
    float x1 = pxc - 0.5f * pw, y1 = pyc - 0.5f * phh;
    float x2 = pxc + 0.5f * pw, y2 = pyc + 0.5f * phh;
    x1 = fminf(fmaxf(x1, 0.f), 1023.f);
    x2 = fminf(fmaxf(x2, 0.f), 1023.f);
    y1 = fminf(fmaxf(y1, 0.f), 1023.f);
    y2 = fminf(fmaxf(y2, 0.f), 1023.f);
    bool valid = ((x2 - x1 + 1.f) >= 16.f) && ((y2 - y1 + 1.f) >= 16.f);
    float sc = valid ? s : -__builtin_huge_valf();

    u32 sb  = __float_as_uint(sc);
    u32 ord = (sb & 0x80000000u) ? ~sb : (sb | 0x80000000u);
    u64 key = ((u64)ord << 32) | (u32)(~(u32)i);
    keys[i]  = key;
    boxes[i] = make_float4(x1, y1, x2, y2);

    u64 infb = __ballot(!valid);
    if (valid) {
        atomicAdd(&lh[binof(ord)], 1u);
    } else {
        if (lane == __builtin_ctzll(infb))
            atomicAdd(&lh[0], (u32)__popcll(infb));
    }
    __syncthreads();
    for (int b = t; b < NBIN; b += 256) {
        u32 x = lh[b];
        if (x) atomicAdd(&hist[b], x);
    }
}

// ================= K2: descending exclusive scan (verified r6/r7, 1 block) ===
__global__ __launch_bounds__(256) void scan_kernel(const u32* __restrict__ hist,
                                                   u32* __restrict__ binStart,
                                                   u32* __restrict__ gEV) {
    __shared__ u32 wsum[4];
    const int t = threadIdx.x;
    const int lane = t & 63;
    const int v = t >> 6;
    if (t == 0) gEV[1] = KTOP;
    int hi = NBIN - 1 - (NBIN / 256) * t;     // thread t owns 20 bins, descending
    u32 cnt[NBIN / 256];
    u32 sum = 0;
#pragma unroll
    for (int k = 0; k < NBIN / 256; ++k) { cnt[k] = hist[hi - k]; sum += cnt[k]; }
    u32 s = sum;
#pragma unroll
    for (int d = 1; d < 64; d <<= 1) {
        u32 x = __shfl_up(s, d, 64);
        if (lane >= d) s += x;
    }
    if (lane == 63) wsum[v] = s;
    __syncthreads();
    u32 base = 0;
#pragma unroll
    for (int q = 0; q < 4; ++q) { u32 x = wsum[q]; if (q < v) base += x; }
    u32 run = base + s - sum;                 // exclusive (sum of all higher bins)
#pragma unroll
    for (int k = 0; k < NBIN / 256; ++k) {
        int b = hi - k;
        binStart[b] = run;
        u32 end = run + cnt[k];
        if (run < KTOP && end >= KTOP) gEV[0] = end;   // unique boundary bucket
        run = end;
    }
}

// ================= K3: scatter (verified r6/r7) ==============================
__global__ __launch_bounds__(256) void scatter_kernel(const u64* __restrict__ keys,
                                                      const u32* __restrict__ binStart,
                                                      u32* __restrict__ cursor,
                                                      u64* __restrict__ scat) {
    int i = blockIdx.x * 256 + threadIdx.x;
    u64 k = keys[i];
    u32 b = binof((u32)(k >> 32));
    u32 s0 = binStart[b];
    if (s0 < KTOP) {
        u32 p = s0 + atomicAdd(&cursor[b], 1u);
        scat[p] = k;
    }
}

// ================= K4: exact rank + gather (verified r6/r7) ==================
__global__ __launch_bounds__(256) void rank_kernel(const u64* __restrict__ scat,
                                                   const u32* __restrict__ binStart,
                                                   const u32* __restrict__ hist,
                                                   const float4* __restrict__ boxes,
                                                   u32* __restrict__ gEV,
                                                   float4* __restrict__ topBoxes) {
    int i = blockIdx.x * 256 + threadIdx.x;
    u32 E = gEV[0];
    if (i >= (int)E) return;
    u64 k = scat[i];
    u32 b = binof((u32)(k >> 32));
    u32 s0 = binStart[b], c = hist[b];
    u32 r = s0;
    for (u32 j = s0; j < s0 + c; ++j) r += (scat[j] > k) ? 1u : 0u;
    if (r < KTOP) {
        int idx = (int)(~(u32)k);
        topBoxes[r] = boxes[idx];
        if (!(k >> 63)) atomicMin((int*)&gEV[1], (int)r);   // first -inf rank => V
    }
}

// ================= K5: transposed mask via shfl (verified r6/r7) =============
// S[w][j] bit b = IoU(box_{64w+b}, box_j)>0.7 && 64w+b<j. Task=(jc,w), w<=jc.
// 1120 blocks x 4 waves: one task per wave, single pass.
__global__ __launch_bounds__(256) void maskT_kernel(const float4* __restrict__ topBoxes,
                                                    const u32* __restrict__ gEV,
                                                    u64* __restrict__ S) {
    const int V = (int)gEV[1];
    const int nch = (V + 63) >> 6;
    const int ntask = nch * (nch + 1) / 2;
    const int lane = threadIdx.x & 63;
    const int v = threadIdx.x >> 6;
    for (int tk = blockIdx.x * 4 + v; tk < ntask; tk += gridDim.x * 4) {
        int jc = (int)((sqrtf(8.f * (float)tk + 1.f) - 1.f) * 0.5f);
        while ((jc + 1) * (jc + 2) / 2 <= tk) ++jc;
        while (jc * (jc + 1) / 2 > tk) --jc;
        int w = tk - jc * (jc + 1) / 2;
        int ci = w * 64 + lane;
        float4 bi = (ci < V) ? topBoxes[ci] : make_float4(0.f, 0.f, -8.f, -8.f);
        float ai = (bi.z - bi.x + 1.f) * (bi.w - bi.y + 1.f);
        int j = jc * 64 + lane;
        float4 bj = (j < V) ? topBoxes[j] : make_float4(0.f, 0.f, -8.f, -8.f);
        float aj = (bj.z - bj.x + 1.f) * (bj.w - bj.y + 1.f);
        u64 m = 0;
#pragma unroll 4
        for (int b = 0; b < 64; ++b) {
            float4 bb;
            bb.x = __shfl(bi.x, b, 64); bb.y = __shfl(bi.y, b, 64);
            bb.z = __shfl(bi.z, b, 64); bb.w = __shfl(bi.w, b, 64);
            float ab = __shfl(ai, b, 64);
            if (iou_gt(bb, ab, bj, aj)) m |= (1ull << b);
        }
        if (w == jc) m &= ((1ull << lane) - 1ull);   // diag word: only i < j
        S[(u64)w * NJ + j] = m;
    }
}

// ---- NMS named-register slot machinery (rule #20: named scalars, not arrays —
// r3-r5's u64 arrays went to scratch, VGPR_Count 40/44 proved it; named-reg
// version verified in r6/r7).
#define SLOT_DECL(K) u64 kw##K = 0, pa##K = 0, pb##K = 0; u32 ao##K = 0;
#define SLOT_ACC(K)  if (nslot > 4*(K) + v) { accA |= pa##K & kw##K; accB |= pb##K & kw##K; }
#define SLOT_REF(K)  if (nslot > 4*(K) + v) { const u64* rp_ = S + (u64)ao##K * NJ + ofsn; pa##K = rp_[0]; pb##K = rp_[64]; }
#define SLOT_CASE(K) case K: kw##K = kb_; ao##K = wch_; if (pf_) { const u64* rp_ = S + (u64)wch_ * NJ + onx_; pa##K = rp_[0]; pb##K = rp_[64]; } break;
#define DO_CLAIM(KB, WCH) do {                                                \
    u64 kb_ = (KB); u32 wch_ = (WCH);                                         \
    int si_ = nslot >> 2, so_ = nslot & 3;                                    \
    if (si_ < NSLOT) {                                                        \
      if (v == so_) {                                                         \
        bool pf_ = (r + 1 < nr);                                              \
        u64 onx_ = (u64)(128 * (r + 1)) + lane;                               \
        switch (si_) {                                                        \
          SLOT_CASE(0) SLOT_CASE(1) SLOT_CASE(2) SLOT_CASE(3)                 \
          SLOT_CASE(4) SLOT_CASE(5) SLOT_CASE(6) SLOT_CASE(7)                 \
          SLOT_CASE(8) SLOT_CASE(9) SLOT_CASE(10) SLOT_CASE(11)               \
          default: break;                                                     \
        }                                                                     \
      }                                                                       \
      ++nslot;                                                                \
    } else if (nspill < SPILLCAP) {                                           \
      if (v == 3 && lane == 0) { spillW[nspill] = wch_; spillK[nspill] = kb_; } \
      ++nspill; sadd = true;                                                  \
    }                                                                         \
  } while (0)

// ================= K6: greedy NMS + output (verified r7, 1 block) ============
__global__ __launch_bounds__(256, 1) void nms_out_kernel(const float4* __restrict__ topBoxes,
                                                         const u32* __restrict__ gEV,
                                                         const u64* __restrict__ S,
                                                         float* __restrict__ out) {
    __shared__ u64 keepw[NCHK];
    __shared__ u64 supw[2][8];               // parity x (A:0..3 | B:4..7)
    __shared__ u64 spillK[SPILLCAP];
    __shared__ u32 spillW[SPILLCAP];
    __shared__ u32 wsum[4];
    const int t = threadIdx.x;
    const int lane = t & 63;
    const int v = t >> 6;                    // 4 waves
    const int V = (int)gEV[1];
    const int nch = (V + 63) >> 6;
    const int nr  = (nch + 1) >> 1;          // pair rounds
    if (t < NCHK) keepw[t] = 0;

    SLOT_DECL(0) SLOT_DECL(1) SLOT_DECL(2) SLOT_DECL(3)
    SLOT_DECL(4) SLOT_DECL(5) SLOT_DECL(6) SLOT_DECL(7)
    SLOT_DECL(8) SLOT_DECL(9) SLOT_DECL(10) SLOT_DECL(11)

    // diagonal words for round r, depth-1 prefetched (kept-independent addresses)
    u64 dAc  = S[lane];                      // S[0][0..63]
    u64 dABc = S[64 + lane];                 // S[0][64..127]
    u64 dBc  = S[(u64)NJ + 64 + lane];       // S[1][64..127]
    int nslot = 0, nspill = 0, nkept = 0;    // uniform & identical across waves

    for (int r = 0; r < nr; ++r) {
        const int par = r & 1;
        u64 accA = 0, accB = 0;
        SLOT_ACC(0) SLOT_ACC(1) SLOT_ACC(2) SLOT_ACC(3)
        SLOT_ACC(4) SLOT_ACC(5) SLOT_ACC(6) SLOT_ACC(7)
        SLOT_ACC(8) SLOT_ACC(9) SLOT_ACC(10) SLOT_ACC(11)
        for (int s2 = v; s2 < nspill; s2 += 4) {      // fallback (rarely active)
            u64 kk = spillK[s2];
            const u64* row = S + (u64)spillW[s2] * NJ + 128 * r + lane;
            accA |= row[0] & kk; accB |= row[64] & kk;
        }
        u64 bA = __ballot(accA != 0ull), bB = __ballot(accB != 0ull);
        if (lane == 0) { supw[par][v] = bA; supw[par][4 + v] = bB; }
        u64 dAn = 0, dABn = 0, dBn = 0;
        if (r + 1 < nr) {                    // refill prefetches for round r+1
            u64 ofsn = (u64)(128 * (r + 1)) + lane;
            SLOT_REF(0) SLOT_REF(1) SLOT_REF(2) SLOT_REF(3)
            SLOT_REF(4) SLOT_REF(5) SLOT_REF(6) SLOT_REF(7)
            SLOT_REF(8) SLOT_REF(9) SLOT_REF(10) SLOT_REF(11)
            int rn = r + 1;
            dAn  = S[(u64)(2 * rn) * NJ + 128 * rn + lane];
            dABn = S[(u64)(2 * rn) * NJ + 128 * rn + 64 + lane];
            dBn  = S[(u64)(2 * rn + 1) * NJ + 128 * rn + 64 + lane];
        }
        BARRIER_LDS();                       // the only barrier in the round
        u64 rwA = supw[par][0] | supw[par][1] | supw[par][2] | supw[par][3];
        u64 rwB = supw[par][4] | supw[par][5] | supw[par][6] | supw[par][7];
        int remA = V - 128 * r;
        int remB = remA - 64;
        u64 aliveA = (remA >= 64) ? ~0ull : ((remA <= 0) ? 0ull : ((1ull << remA) - 1ull));
        u64 aliveB = (remB >= 64) ? ~0ull : ((remB <= 0) ? 0ull : ((1ull << remB) - 1ull));
        u64 candA = ~rwA & aliveA, kbA = 0;
        while (candA) {
            int b = __builtin_ctzll(candA);
            kbA |= (1ull << b);
            candA &= ~(1ull << b);
            candA &= ~__ballot(((dAc >> b) & 1ull) != 0ull);
        }
        u64 supAB = __ballot((dABc & kbA) != 0ull);
        u64 candB = ~(rwB | supAB) & aliveB, kbB = 0;
        while (candB) {
            int b = __builtin_ctzll(candB);
            kbB |= (1ull << b);
            candB &= ~(1ull << b);
            candB &= ~__ballot(((dBc >> b) & 1ull) != 0ull);
        }
        if (t == 0) { keepw[2 * r] = kbA; if (2 * r + 1 < nch) keepw[2 * r + 1] = kbB; }
        bool sadd = false;
        if (kbA) DO_CLAIM(kbA, (u32)(2 * r));
        if (kbB) DO_CLAIM(kbB, (u32)(2 * r + 1));
        if (sadd) BARRIER_LDS();             // spill entries visible next round
        nkept += __popcll(kbA) + __popcll(kbB);
        dAc = dAn; dABc = dABn; dBc = dBn;
        if (nkept >= NOUT) break;            // uniform (kb identical per wave)
    }
    __syncthreads();

    // output: kept boxes in rank order, then not-kept (suppressed or rank>=V)
    // in rank order, filling up to 300 (verified semantics).
    const int per = 24;                      // 256*24 >= 6000
    int r0 = t * per;
    int r1 = min(r0 + per, KTOP);
    u32 cnt2 = 0;
    for (int rr = r0; rr < r1; ++rr)
        cnt2 += (u32)((keepw[rr >> 6] >> (rr & 63)) & 1ull);
    u32 s2 = cnt2;
#pragma unroll
    for (int d = 1; d < 64; d <<= 1) {
        u32 x = __shfl_up(s2, d, 64);
        if (lane >= d) s2 += x;
    }
    if (lane == 63) wsum[v] = s2;
    __syncthreads();
    u32 base = 0, total = 0;
#pragma unroll
    for (int q = 0; q < 4; ++q) {
        u32 x = wsum[q];
        if (q < v) base += x;
        total += x;
    }
    const int n1 = min((int)total, NOUT);
    int kp = (int)(base + s2 - cnt2);        // kept before r0
    for (int rr = r0; rr < r1; ++rr) {
        int kept = (int)((keepw[rr >> 6] >> (rr & 63)) & 1ull);
        int pos = kept ? kp : (n1 + rr - kp);
        if (pos < NOUT) {
            float4 b = topBoxes[rr];
            out[pos * 5 + 0] = 0.f;
            out[pos * 5 + 1] = b.x; out[pos * 5 + 2] = b.y;
            out[pos * 5 + 3] = b.z; out[pos * 5 + 4] = b.w;
        }
        kp += kept;
    }
}

extern "C" void kernel_launch(void* const* d_in, const int* in_sizes, int n_in,
                              void* d_out, int out_size, void* d_ws, size_t ws_size,
                              hipStream_t stream) {
    const float* cls = (const float*)d_in[0];   // (1,64,64,18) f32
    const float* dlt = (const float*)d_in[1];   // (1,64,64,36) f32
    float* out = (float*)d_out;                 // 300x5 f32
    char* ws = (char*)d_ws;
    u64*    keys     = (u64*)   (ws);                    // 294912
    u64*    scat     = (u64*)   (ws + 294912);           // 294912
    float4* boxes    = (float4*)(ws + 589824);           // 589824
    float4* topBoxes = (float4*)(ws + 1179648);          // 96000
    u32*    hist     = (u32*)   (ws + 1275648);          // 20480
    u32*    cursor   = (u32*)   (ws + 1296128);          // 20480 (contiguous after hist)
    u32*    binStart = (u32*)   (ws + 1316608);          // 20480
    u32*    gEV      = (u32*)   (ws + 1337088);          // [0]=E, [1]=V
    u64*    S        = (u64*)   (ws + 1337344);          // 4524032 (94 x 6016 words)

    hipMemsetAsync(hist, 0, 2 * NBIN * sizeof(u32), stream);   // hist + cursor
    proposal_kernel<<<144, 256, 0, stream>>>(cls, dlt, keys, boxes, hist);
    scan_kernel<<<1, 256, 0, stream>>>(hist, binStart, gEV);
    scatter_kernel<<<144, 256, 0, stream>>>(keys, binStart, cursor, scat);
    rank_kernel<<<144, 256, 0, stream>>>(scat, binStart, hist, boxes, gEV, topBoxes);
    maskT_kernel<<<1120, 256, 0, stream>>>(topBoxes, gEV, S);
    nms_out_kernel<<<1, 256, 0, stream>>>(topBoxes, gEV, S, out);
}